// Round 2
// baseline (242.944 us; speedup 1.0000x reference)
//
#include <hip/hip_runtime.h>

// GraphSAGE 3-layer forward: N=50000 nodes, E=800000 edges, F: 96->96->96->48
// out_i = relu( mean_{j in N(i)} h_j @ Wl + h_i @ Wr + b ), x3 layers.
//
// R14: atomic-free adjacency build. R12/R13 both spent ~45us in build despite
// write-amp fix -> cost is the 800K device-scope atomicAdd-with-return ops
// (serialize at chip coherence point, ~8-10/cy => ~40us floor). Now:
//  Phase A (in grid with cvt/WT): 625 blocks bucket edges by dst/6250 into
//    fixed per-(block,bucket) 256-slot segments via LDS atomics only; packed
//    (dstrel<<16)|src u32 + per-segment counts. Zero global atomics.
//  Phase B: 256 blocks; block b -> XCD b&7 owns 196 nodes of that XCD's
//    range; scans bucket b&7 (640KB, L2-local) wave-per-segment with
//    prefetch; LDS-atomic slotting into LDS colu (25KB); coalesced dump of
//    colu+deg. deg fully written -> memset dropped.
// Gather/MFMA layers unchanged from R7.

#define NNODES 50000
#define NROWS  50001        // h rows incl. sentinel
#define ZROW   50000        // sentinel row (all zeros) in each h buffer
#define NEDGES 800000
#define CAP    64           // per-node adjacency capacity (max deg ~40 w.h.p.)
#define LSTR   72           // LDS cols stride in ushorts (144B -> bank-spread)
#define NPX    6250         // nodes per XCD partition (8*6250 = 50000 exact)
#define EBA    625          // phase-A edge blocks
#define EPBA   1280         // edges per phase-A block (5/thread, 625*1280=800000)
#define SEGS   625          // segments per bucket (= EBA)
#define SEGC   256          // slots per (block,bucket) segment
#define BNODE  196          // nodes per phase-B block (196*32 >= 6250)
#define CVT_N8 600000       // 50000*96/8
#define CB 2344             // ceil(600000/256)
#define WTN 46080           // 2*96*192 + 48*192
#define WB 180              // ceil(46080/256)

typedef __attribute__((ext_vector_type(8))) short bf16x8;
typedef __attribute__((ext_vector_type(4))) float f32x4;

__device__ inline unsigned short f2bf(float f) {
    unsigned int u = __float_as_uint(f);
    unsigned int r = (u + 0x7fffu + ((u >> 16) & 1u)) >> 16;   // RNE
    return (unsigned short)r;
}
__device__ inline float bf2f_lo(unsigned int u) { return __uint_as_float(u << 16); }
__device__ inline float bf2f_hi(unsigned int u) { return __uint_as_float(u & 0xffff0000u); }

// ---------------- pass 1a: edge bucketing (LDS atomics) + converts + zero-rows ----------------
// blocks [0,EBA): edge bucket; [EBA,EBA+CB): x->bf16; next WB: WT prep; last 1: sentinel.
__global__ void build_a(const int* __restrict__ src, const int* __restrict__ dst,
                        unsigned int* __restrict__ region, int* __restrict__ cnta,
                        const float* __restrict__ x, unsigned short* __restrict__ h0b,
                        unsigned short* __restrict__ h1b, unsigned short* __restrict__ h2b,
                        const float* __restrict__ Wl0, const float* __restrict__ Wr0,
                        const float* __restrict__ Wl1, const float* __restrict__ Wr1,
                        const float* __restrict__ Wl2, const float* __restrict__ Wr2,
                        unsigned short* __restrict__ WT0, unsigned short* __restrict__ WT1,
                        unsigned short* __restrict__ WT2) {
    int b = blockIdx.x;
    if (b < EBA) {
        __shared__ int hist[8];
        const int t = threadIdx.x;
        if (t < 8) hist[t] = 0;
        __syncthreads();
        const int e0 = b * EPBA;
        int dv[5], sv[5];
#pragma unroll
        for (int i = 0; i < 5; ++i) {
            dv[i] = dst[e0 + i * 256 + t];
            sv[i] = src[e0 + i * 256 + t];
        }
#pragma unroll
        for (int i = 0; i < 5; ++i) {
            unsigned int d = (unsigned int)dv[i];
            unsigned int xb = d / 6250u;                 // bucket = dst XCD range
            unsigned int rel = d - xb * 6250u;           // 13 bits
            unsigned int val = (rel << 16) | (unsigned int)sv[i];
            int r = atomicAdd(&hist[xb], 1);             // LDS atomic, fast
            if (r < SEGC) region[((size_t)xb * SEGS + b) * SEGC + r] = val;
        }
        __syncthreads();
        if (t < 8) cnta[b * 8 + t] = min(hist[t], SEGC);
    } else if (b < EBA + CB) {
        long long t = (long long)(b - EBA) * 256 + threadIdx.x;
        if (t < CVT_N8) {
            const float4* p = reinterpret_cast<const float4*>(x + t * 8);
            float4 a = p[0], c = p[1];
            uint4 o;
            o.x = (unsigned)f2bf(a.x) | ((unsigned)f2bf(a.y) << 16);
            o.y = (unsigned)f2bf(a.z) | ((unsigned)f2bf(a.w) << 16);
            o.z = (unsigned)f2bf(c.x) | ((unsigned)f2bf(c.y) << 16);
            o.w = (unsigned)f2bf(c.z) | ((unsigned)f2bf(c.w) << 16);
            *reinterpret_cast<uint4*>(h0b + t * 8) = o;
        }
    } else if (b < EBA + CB + WB) {
        int t = (b - EBA - CB) * 256 + threadIdx.x;
        if (t >= WTN) return;
        const float* Wl; const float* Wr; unsigned short* WT; int fout; int u;
        if (t < 18432)      { Wl = Wl0; Wr = Wr0; WT = WT0; fout = 96; u = t; }
        else if (t < 36864) { Wl = Wl1; Wr = Wr1; WT = WT1; fout = 96; u = t - 18432; }
        else                { Wl = Wl2; Wr = Wr2; WT = WT2; fout = 48; u = t - 36864; }
        int j = u / 192;
        int k = u - j * 192;
        float v = (k < 96) ? Wl[k * fout + j] : Wr[(k - 96) * fout + j];
        WT[u] = f2bf(v);
    } else {
        // zero the sentinel rows: 3 buffers x 96 shorts = 36 uint4 stores
        int t = threadIdx.x;
        if (t < 36) {
            uint4 z = make_uint4(0, 0, 0, 0);
            unsigned short* base = (t < 12) ? h0b : (t < 24) ? h1b : h2b;
            int c = (t % 12) * 8;
            *reinterpret_cast<uint4*>(base + (size_t)ZROW * 96 + c) = z;
        }
    }
}

// ---------------- pass 1b: per-node slotting via LDS atomics ----------------
// 256 blocks; block b -> XCD x=b&7 (hw round-robin), subrange j=b>>3 of 196
// nodes in [x*6250, (x+1)*6250). Scans bucket x (L2-local: 32 blocks of the
// same XCD share it). Wave w handles segments w, w+4, ... with one uint4
// (4 edges) per lane, prefetched one iteration ahead for MLP.
__global__ __launch_bounds__(256) void build_b(const unsigned int* __restrict__ region,
                                               const int* __restrict__ cnta,
                                               int* __restrict__ deg,
                                               unsigned short* __restrict__ colu) {
    __shared__ int cnts[SEGS];
    __shared__ int deg_l[BNODE];
    __shared__ __attribute__((aligned(16))) unsigned short colu_l[BNODE * CAP];
    const int b = blockIdx.x;
    const int x = b & 7;            // bucket == XCD
    const int j = b >> 3;           // subrange within partition
    const int t = threadIdx.x;
    const int base_node = x * NPX + j * BNODE;
    const int nn = min(BNODE, NPX - j * BNODE);   // 196, last block 174
    for (int s = t; s < SEGS; s += 256) cnts[s] = cnta[s * 8 + x];
    if (t < BNODE) deg_l[t] = 0;
    __syncthreads();

    const int w = t >> 6, lane = t & 63;
    const int jbase = j * BNODE;
    const size_t bb = (size_t)x * SEGS;
    int s = w;
    uint4 v = make_uint4(0, 0, 0, 0);
    int c = 0;
    if (s < SEGS) {
        v = *reinterpret_cast<const uint4*>(region + (bb + s) * SEGC + lane * 4);
        c = cnts[s];
    }
    while (s < SEGS) {
        const int sn = s + 4;
        uint4 vn = make_uint4(0, 0, 0, 0);
        int cn = 0;
        if (sn < SEGS) {                          // prefetch next segment
            vn = *reinterpret_cast<const uint4*>(region + (bb + sn) * SEGC + lane * 4);
            cn = cnts[sn];
        }
        const int idx = lane * 4;
        const unsigned int vv0 = v.x, vv1 = v.y, vv2 = v.z, vv3 = v.w;
        if (idx + 0 < c) {
            int local = (int)(vv0 >> 16) - jbase;
            if ((unsigned)local < (unsigned)nn) {
                int r = atomicAdd(&deg_l[local], 1);
                if (r < CAP) colu_l[local * CAP + r] = (unsigned short)(vv0 & 0xffffu);
            }
        }
        if (idx + 1 < c) {
            int local = (int)(vv1 >> 16) - jbase;
            if ((unsigned)local < (unsigned)nn) {
                int r = atomicAdd(&deg_l[local], 1);
                if (r < CAP) colu_l[local * CAP + r] = (unsigned short)(vv1 & 0xffffu);
            }
        }
        if (idx + 2 < c) {
            int local = (int)(vv2 >> 16) - jbase;
            if ((unsigned)local < (unsigned)nn) {
                int r = atomicAdd(&deg_l[local], 1);
                if (r < CAP) colu_l[local * CAP + r] = (unsigned short)(vv2 & 0xffffu);
            }
        }
        if (idx + 3 < c) {
            int local = (int)(vv3 >> 16) - jbase;
            if ((unsigned)local < (unsigned)nn) {
                int r = atomicAdd(&deg_l[local], 1);
                if (r < CAP) colu_l[local * CAP + r] = (unsigned short)(vv3 & 0xffffu);
            }
        }
        v = vn; c = cn; s = sn;
    }
    __syncthreads();

    // coalesced dump: colu rows for [base_node, base_node+nn), then deg
    for (int i = t; i < nn * (CAP / 8); i += 256) {
        *reinterpret_cast<uint4*>(colu + (size_t)base_node * CAP + i * 8) =
            *reinterpret_cast<const uint4*>(colu_l + i * 8);
    }
    if (t < nn) deg[base_node + t] = deg_l[t];
}

// ---------------- fused gather-mean + dual MFMA GEMM + bias + relu ----------------
// Block = 16 nodes, 256 threads. Stage 16*CAP ushort slots (2 KB) into LDS
// (stride LSTR, sanitized: slot>=deg -> ZROW). Threads 0..191 gather-mean
// (8-wide, 8 outstanding 16B loads) into Asm; 4 waves run the K=192
// [mean|h] @ [Wl;Wr] MFMA, N-tiles strided across waves.
// A-frag (16x16x32 bf16): lane holds A[m=lane&15][k=(lane>>4)*8+0..7]
// B-frag: lane holds B[k=(lane>>4)*8+0..7][n=lane&15] -> WT[n][k] rows
// C/D: col=lane&15, row=(lane>>4)*4+reg  (verified layout, m89)
template <int NT, bool WRITE_BF16>
__global__ __launch_bounds__(256) void fused_layer(
    const unsigned short* __restrict__ hb,
    const int* __restrict__ deg, const unsigned short* __restrict__ colu,
    const unsigned short* __restrict__ WT,   // [16*NT][192]
    const float* __restrict__ bias,          // [16*NT]
    unsigned short* __restrict__ out_bf, float* __restrict__ out_f) {
    __shared__ unsigned short Asm[16][200];
    __shared__ unsigned short cols[16 * LSTR];
    const int i0 = blockIdx.x * 16;
    const int t = threadIdx.x;

    // ---- stage + sanitize adjacency: 1024 ushorts, 4 per thread ----
    {
        int u4 = t * 4;                      // ushort index 0..1020
        int node = u4 >> 6;                  // CAP=64
        int slot = u4 & 63;
        uint2 v = *reinterpret_cast<const uint2*>(colu + (size_t)(i0 + node) * CAP + slot);
        int d = deg[i0 + node];
        unsigned int s0 = (slot + 0 < d) ? (v.x & 0xffffu) : ZROW;
        unsigned int s1 = (slot + 1 < d) ? (v.x >> 16)     : ZROW;
        unsigned int s2 = (slot + 2 < d) ? (v.y & 0xffffu) : ZROW;
        unsigned int s3 = (slot + 3 < d) ? (v.y >> 16)     : ZROW;
        uint2 o;
        o.x = s0 | (s1 << 16);
        o.y = s2 | (s3 << 16);
        *reinterpret_cast<uint2*>(&cols[node * LSTR + slot]) = o;
    }
    __syncthreads();

    if (t < 192) {
        const int nl = t / 12;
        const int c = (t - nl * 12) * 8;
        const int d = deg[i0 + nl];
        const int pd = (d + 7) & ~7;
        float a0 = 0.f, a1 = 0.f, a2 = 0.f, a3 = 0.f, a4 = 0.f, a5 = 0.f, a6 = 0.f, a7 = 0.f;
        for (int j = 0; j < pd; j += 8) {
            uint4 cu = *reinterpret_cast<const uint4*>(&cols[nl * LSTR + j]);
            int s0 = (int)(cu.x & 0xffffu), s1 = (int)(cu.x >> 16);
            int s2 = (int)(cu.y & 0xffffu), s3 = (int)(cu.y >> 16);
            int s4 = (int)(cu.z & 0xffffu), s5 = (int)(cu.z >> 16);
            int s6 = (int)(cu.w & 0xffffu), s7 = (int)(cu.w >> 16);
            uint4 u0 = *reinterpret_cast<const uint4*>(hb + (size_t)s0 * 96 + c);
            uint4 u1 = *reinterpret_cast<const uint4*>(hb + (size_t)s1 * 96 + c);
            uint4 u2 = *reinterpret_cast<const uint4*>(hb + (size_t)s2 * 96 + c);
            uint4 u3 = *reinterpret_cast<const uint4*>(hb + (size_t)s3 * 96 + c);
            uint4 u4 = *reinterpret_cast<const uint4*>(hb + (size_t)s4 * 96 + c);
            uint4 u5 = *reinterpret_cast<const uint4*>(hb + (size_t)s5 * 96 + c);
            uint4 u6 = *reinterpret_cast<const uint4*>(hb + (size_t)s6 * 96 + c);
            uint4 u7 = *reinterpret_cast<const uint4*>(hb + (size_t)s7 * 96 + c);
            a0 += bf2f_lo(u0.x) + bf2f_lo(u1.x) + bf2f_lo(u2.x) + bf2f_lo(u3.x)
                + bf2f_lo(u4.x) + bf2f_lo(u5.x) + bf2f_lo(u6.x) + bf2f_lo(u7.x);
            a1 += bf2f_hi(u0.x) + bf2f_hi(u1.x) + bf2f_hi(u2.x) + bf2f_hi(u3.x)
                + bf2f_hi(u4.x) + bf2f_hi(u5.x) + bf2f_hi(u6.x) + bf2f_hi(u7.x);
            a2 += bf2f_lo(u0.y) + bf2f_lo(u1.y) + bf2f_lo(u2.y) + bf2f_lo(u3.y)
                + bf2f_lo(u4.y) + bf2f_lo(u5.y) + bf2f_lo(u6.y) + bf2f_lo(u7.y);
            a3 += bf2f_hi(u0.y) + bf2f_hi(u1.y) + bf2f_hi(u2.y) + bf2f_hi(u3.y)
                + bf2f_hi(u4.y) + bf2f_hi(u5.y) + bf2f_hi(u6.y) + bf2f_hi(u7.y);
            a4 += bf2f_lo(u0.z) + bf2f_lo(u1.z) + bf2f_lo(u2.z) + bf2f_lo(u3.z)
                + bf2f_lo(u4.z) + bf2f_lo(u5.z) + bf2f_lo(u6.z) + bf2f_lo(u7.z);
            a5 += bf2f_hi(u0.z) + bf2f_hi(u1.z) + bf2f_hi(u2.z) + bf2f_hi(u3.z)
                + bf2f_hi(u4.z) + bf2f_hi(u5.z) + bf2f_hi(u6.z) + bf2f_hi(u7.z);
            a6 += bf2f_lo(u0.w) + bf2f_lo(u1.w) + bf2f_lo(u2.w) + bf2f_lo(u3.w)
                + bf2f_lo(u4.w) + bf2f_lo(u5.w) + bf2f_lo(u6.w) + bf2f_lo(u7.w);
            a7 += bf2f_hi(u0.w) + bf2f_hi(u1.w) + bf2f_hi(u2.w) + bf2f_hi(u3.w)
                + bf2f_hi(u4.w) + bf2f_hi(u5.w) + bf2f_hi(u6.w) + bf2f_hi(u7.w);
        }
        float inv = (d > 0) ? 1.0f / (float)d : 0.0f;
        uint4 o;
        o.x = (unsigned)f2bf(a0 * inv) | ((unsigned)f2bf(a1 * inv) << 16);
        o.y = (unsigned)f2bf(a2 * inv) | ((unsigned)f2bf(a3 * inv) << 16);
        o.z = (unsigned)f2bf(a4 * inv) | ((unsigned)f2bf(a5 * inv) << 16);
        o.w = (unsigned)f2bf(a6 * inv) | ((unsigned)f2bf(a7 * inv) << 16);
        *reinterpret_cast<uint4*>(&Asm[nl][c]) = o;
    }
    __syncthreads();

    const int wave = t >> 6;
    const int lane = t & 63;
    const int m = lane & 15;
    const int kq = (lane >> 4) * 8;

    bf16x8 afr[6];
#pragma unroll
    for (int kk = 0; kk < 3; ++kk)
        afr[kk] = *reinterpret_cast<const bf16x8*>(&Asm[m][kq + kk * 32]);
    const unsigned short* hrow = hb + (size_t)(i0 + m) * 96 + kq;
#pragma unroll
    for (int kk = 0; kk < 3; ++kk)
        afr[3 + kk] = *reinterpret_cast<const bf16x8*>(hrow + kk * 32);

    const int r0 = (lane >> 4) * 4;
    for (int nt = wave; nt < NT; nt += 4) {
        f32x4 acc = {0.f, 0.f, 0.f, 0.f};
        const unsigned short* wrow = WT + (size_t)(nt * 16 + m) * 192 + kq;
#pragma unroll
        for (int kk = 0; kk < 6; ++kk) {
            bf16x8 bfr = *reinterpret_cast<const bf16x8*>(wrow + kk * 32);
            acc = __builtin_amdgcn_mfma_f32_16x16x32_bf16(afr[kk], bfr, acc, 0, 0, 0);
        }
        int colj = nt * 16 + m;
        float bv = bias[colj];
#pragma unroll
        for (int r = 0; r < 4; ++r) {
            float v = fmaxf(acc[r] + bv, 0.0f);
            size_t oi = (size_t)(i0 + r0 + r) * (16 * NT) + colj;
            if (WRITE_BF16) out_bf[oi] = f2bf(v);
            else            out_f[oi] = v;
        }
    }
}

extern "C" void kernel_launch(void* const* d_in, const int* in_sizes, int n_in,
                              void* d_out, int out_size, void* d_ws, size_t ws_size,
                              hipStream_t stream) {
    const float* x   = (const float*)d_in[0];
    const int*   ei  = (const int*)d_in[1];   // [2, E]: row0 = src, row1 = dst
    const float* Wl0 = (const float*)d_in[2];
    const float* Wr0 = (const float*)d_in[3];
    const float* b0  = (const float*)d_in[4];
    const float* Wl1 = (const float*)d_in[5];
    const float* Wr1 = (const float*)d_in[6];
    const float* b1  = (const float*)d_in[7];
    const float* Wl2 = (const float*)d_in[8];
    const float* Wr2 = (const float*)d_in[9];
    const float* b2  = (const float*)d_in[10];
    float* out = (float*)d_out;

    const int* src = ei;
    const int* dst = ei + NEDGES;

    // workspace layout (all sizes multiples of 64 B)
    char* p = (char*)d_ws;
    int* deg = (int*)p;                        p += (size_t)50176 * 4;            // 200 KB
    unsigned short* colu = (unsigned short*)p; p += (size_t)50176 * CAP * 2;      // 6.4 MB
    unsigned int* region = (unsigned int*)p;   p += (size_t)8 * SEGS * SEGC * 4;  // 5.12 MB
    int* cnta = (int*)p;                       p += (size_t)20032;                // 625*8*4 padded
    unsigned short* WT0 = (unsigned short*)p;  p += 96 * 192 * 2;
    unsigned short* WT1 = (unsigned short*)p;  p += 96 * 192 * 2;
    unsigned short* WT2 = (unsigned short*)p;  p += 48 * 192 * 2;
    unsigned short* h0b = (unsigned short*)p;  p += (size_t)NROWS * 96 * 2 + 64;
    unsigned short* h1b = (unsigned short*)p;  p += (size_t)NROWS * 96 * 2 + 64;
    unsigned short* h2b = (unsigned short*)p;  p += (size_t)NROWS * 96 * 2 + 64;

    // ---- phase A: edge bucketing + converts (one grid, no global atomics) ----
    build_a<<<EBA + CB + WB + 1, 256, 0, stream>>>(
        src, dst, region, cnta, x, h0b, h1b, h2b,
        Wl0, Wr0, Wl1, Wr1, Wl2, Wr2, WT0, WT1, WT2);

    // ---- phase B: per-node slotting (LDS atomics, XCD-local) ----
    build_b<<<256, 256, 0, stream>>>(region, cnta, deg, colu);

    // ---- layers (fused gather + MFMA), 16 nodes / 256 threads per block ----
    const int LB = NNODES / 16;   // 3125 exact
    fused_layer<6, true><<<LB, 256, 0, stream>>>(h0b, deg, colu, WT0, b0, h1b, nullptr);
    fused_layer<6, true><<<LB, 256, 0, stream>>>(h1b, deg, colu, WT1, b1, h2b, nullptr);
    fused_layer<3, false><<<LB, 256, 0, stream>>>(h2b, deg, colu, WT2, b2, nullptr, out);
}

// Round 3
// 200.380 us; speedup vs baseline: 1.2124x; 1.2124x over previous
//
#include <hip/hip_runtime.h>

// GraphSAGE 3-layer forward: N=50000 nodes, E=800000 edges, F: 96->96->96->48
// out_i = relu( mean_{j in N(i)} h_j @ Wl + h_i @ Wr + b ), x3 layers.
//
// R15: atomic-free build, fixed decomposition. R13 showed 800K device-scope
// atomicAdd ~44us (7.6/cy chip-wide, locality-independent). R14's two-phase
// failed in phase B: 256 blocks x 32x-redundant 640KB scans at 10% occupancy
// (66us). Now: phase A buckets edges into 512 fine buckets (98 nodes) via
// 512-counter LDS hist, 400 blocks x 2000 edges, 20-slot cells in block-
// private region rows (no cross-XCD sharing). Phase B: 511 blocks, one
// bucket each, reads ONLY its 400 cells (~32KB, L3-hot), LDS-atomic slots
// ~1560 edges into LDS adjacency, coalesced dump. region (16.4MB) aliases
// h1b+h2b (dead until layer outputs); their sentinel rows are zeroed by the
// producing layer kernel. Zero global atomics. Gather/MFMA layers = R7.

#define NNODES 50000
#define NROWS  50001        // h rows incl. sentinel
#define ZROW   50000        // sentinel row (all zeros) in each h buffer
#define NEDGES 800000
#define CAP    64           // per-node adjacency capacity (max deg ~40 w.h.p.)
#define LSTR   72           // LDS cols stride in ushorts (144B -> bank-spread)
#define NBKT   512          // fine buckets
#define BKSZ   98           // nodes per bucket (512*98 >= 50000; max bucket 510)
#define NBKB   511          // phase-B grid (buckets actually populated)
#define EBA    400          // phase-A edge blocks
#define EPBA   2000         // edges per phase-A block (400*2000 = 800000)
#define SEGC   20           // slots per (ablock,bucket) cell (80B, 16B-aligned)
#define CVT_N8 600000       // 50000*96/8
#define CB 2344             // ceil(600000/256)
#define WTN 46080           // 2*96*192 + 48*192
#define WB 180              // ceil(46080/256)

typedef __attribute__((ext_vector_type(8))) short bf16x8;
typedef __attribute__((ext_vector_type(4))) float f32x4;

__device__ inline unsigned short f2bf(float f) {
    unsigned int u = __float_as_uint(f);
    unsigned int r = (u + 0x7fffu + ((u >> 16) & 1u)) >> 16;   // RNE
    return (unsigned short)r;
}
__device__ inline float bf2f_lo(unsigned int u) { return __uint_as_float(u << 16); }
__device__ inline float bf2f_hi(unsigned int u) { return __uint_as_float(u & 0xffff0000u); }

// ---------------- pass 1a: fine-bucket edges (LDS atomics) + converts ----------------
// blocks [0,EBA): edge bucket; [EBA,EBA+CB): x->bf16; next WB: WT prep; last 1: h0b sentinel.
__global__ void build_a(const int* __restrict__ src, const int* __restrict__ dst,
                        unsigned int* __restrict__ region, unsigned char* __restrict__ cnta,
                        const float* __restrict__ x, unsigned short* __restrict__ h0b,
                        const float* __restrict__ Wl0, const float* __restrict__ Wr0,
                        const float* __restrict__ Wl1, const float* __restrict__ Wr1,
                        const float* __restrict__ Wl2, const float* __restrict__ Wr2,
                        unsigned short* __restrict__ WT0, unsigned short* __restrict__ WT1,
                        unsigned short* __restrict__ WT2) {
    int b = blockIdx.x;
    if (b < EBA) {
        __shared__ int hist[NBKT];
        const int t = threadIdx.x;
        for (int k = t; k < NBKT; k += 256) hist[k] = 0;
        __syncthreads();
        const int e0 = b * EPBA;
        for (int i = t; i < EPBA; i += 256) {
            int d = dst[e0 + i];
            int s = src[e0 + i];
            unsigned int bk = (unsigned int)d / 98u;       // magic-mul
            unsigned int rel = (unsigned int)d - bk * 98u; // 7 bits
            unsigned int val = (rel << 16) | (unsigned int)s;
            int r = atomicAdd(&hist[bk], 1);               // LDS atomic
            if (r < SEGC) region[((size_t)b * NBKT + bk) * SEGC + r] = val;
        }
        __syncthreads();
        for (int k = t; k < NBKT; k += 256)
            cnta[(size_t)k * EBA + b] = (unsigned char)min(hist[k], SEGC);
    } else if (b < EBA + CB) {
        long long t = (long long)(b - EBA) * 256 + threadIdx.x;
        if (t < CVT_N8) {
            const float4* p = reinterpret_cast<const float4*>(x + t * 8);
            float4 a = p[0], c = p[1];
            uint4 o;
            o.x = (unsigned)f2bf(a.x) | ((unsigned)f2bf(a.y) << 16);
            o.y = (unsigned)f2bf(a.z) | ((unsigned)f2bf(a.w) << 16);
            o.z = (unsigned)f2bf(c.x) | ((unsigned)f2bf(c.y) << 16);
            o.w = (unsigned)f2bf(c.z) | ((unsigned)f2bf(c.w) << 16);
            *reinterpret_cast<uint4*>(h0b + t * 8) = o;
        }
    } else if (b < EBA + CB + WB) {
        int t = (b - EBA - CB) * 256 + threadIdx.x;
        if (t >= WTN) return;
        const float* Wl; const float* Wr; unsigned short* WT; int fout; int u;
        if (t < 18432)      { Wl = Wl0; Wr = Wr0; WT = WT0; fout = 96; u = t; }
        else if (t < 36864) { Wl = Wl1; Wr = Wr1; WT = WT1; fout = 96; u = t - 18432; }
        else                { Wl = Wl2; Wr = Wr2; WT = WT2; fout = 48; u = t - 36864; }
        int j = u / 192;
        int k = u - j * 192;
        float v = (k < 96) ? Wl[k * fout + j] : Wr[(k - 96) * fout + j];
        WT[u] = f2bf(v);
    } else {
        // zero the h0b sentinel row (h1b/h2b sentinels are zeroed by the layer
        // kernels that produce those buffers -- region aliases them here)
        int t = threadIdx.x;
        if (t < 12) {
            uint4 z = make_uint4(0, 0, 0, 0);
            *reinterpret_cast<uint4*>(h0b + (size_t)ZROW * 96 + t * 8) = z;
        }
    }
}

// ---------------- pass 1b: per-bucket slotting via LDS atomics ----------------
// 511 blocks; block k owns bucket k (98 nodes). Reads its 400 cells
// (region[b][k][0..cnt) for all ablocks b), LDS-atomic slots into LDS
// adjacency (12.5 KB), coalesced dump of colu + deg. No global atomics.
__global__ __launch_bounds__(256) void build_b(const unsigned int* __restrict__ region,
                                               const unsigned char* __restrict__ cnta,
                                               int* __restrict__ deg,
                                               unsigned short* __restrict__ colu) {
    __shared__ unsigned char cnt_l[EBA];
    __shared__ int deg_l[BKSZ];
    __shared__ __attribute__((aligned(16))) unsigned short colu_l[BKSZ * CAP];
    const int k = blockIdx.x;           // bucket
    const int t = threadIdx.x;
    const int base_node = k * BKSZ;
    const int nn = min(BKSZ, NNODES - base_node);   // 98, last block 20
    for (int i = t; i < EBA; i += 256) cnt_l[i] = cnta[(size_t)k * EBA + i];
    if (t < BKSZ) deg_l[t] = 0;
    __syncthreads();

    for (int cb = t; cb < EBA; cb += 256) {
        const int c = cnt_l[cb];
        const unsigned int* cell = region + ((size_t)cb * NBKT + k) * SEGC;
        for (int j = 0; j < c; j += 4) {
            uint4 q = *reinterpret_cast<const uint4*>(cell + j);   // 16B-aligned (SEGC=20)
            unsigned int qq0 = q.x, qq1 = q.y, qq2 = q.z, qq3 = q.w;
            if (j + 0 < c) {
                int local = (int)(qq0 >> 16);
                int r = atomicAdd(&deg_l[local], 1);
                if (r < CAP) colu_l[local * CAP + r] = (unsigned short)(qq0 & 0xffffu);
            }
            if (j + 1 < c) {
                int local = (int)(qq1 >> 16);
                int r = atomicAdd(&deg_l[local], 1);
                if (r < CAP) colu_l[local * CAP + r] = (unsigned short)(qq1 & 0xffffu);
            }
            if (j + 2 < c) {
                int local = (int)(qq2 >> 16);
                int r = atomicAdd(&deg_l[local], 1);
                if (r < CAP) colu_l[local * CAP + r] = (unsigned short)(qq2 & 0xffffu);
            }
            if (j + 3 < c) {
                int local = (int)(qq3 >> 16);
                int r = atomicAdd(&deg_l[local], 1);
                if (r < CAP) colu_l[local * CAP + r] = (unsigned short)(qq3 & 0xffffu);
            }
        }
    }
    __syncthreads();

    // coalesced dump (uninit slots >= deg are sanitized by the layer kernel)
    for (int i = t; i < nn * (CAP / 8); i += 256) {
        *reinterpret_cast<uint4*>(colu + (size_t)base_node * CAP + i * 8) =
            *reinterpret_cast<const uint4*>(colu_l + i * 8);
    }
    if (t < nn) deg[base_node + t] = deg_l[t];
}

// ---------------- fused gather-mean + dual MFMA GEMM + bias + relu ----------------
// Block = 16 nodes, 256 threads. Stage 16*CAP ushort slots (2 KB) into LDS
// (stride LSTR, sanitized: slot>=deg -> ZROW). Threads 0..191 gather-mean
// (8-wide, 8 outstanding 16B loads) into Asm; 4 waves run the K=192
// [mean|h] @ [Wl;Wr] MFMA, N-tiles strided across waves.
// A-frag (16x16x32 bf16): lane holds A[m=lane&15][k=(lane>>4)*8+0..7]
// B-frag: lane holds B[k=(lane>>4)*8+0..7][n=lane&15] -> WT[n][k] rows
// C/D: col=lane&15, row=(lane>>4)*4+reg  (verified layout, m89)
// When WRITE_BF16, block 0 also zeros the output buffer's sentinel row
// (consumed by the NEXT layer's gather; this kernel never reads it).
template <int NT, bool WRITE_BF16>
__global__ __launch_bounds__(256) void fused_layer(
    const unsigned short* __restrict__ hb,
    const int* __restrict__ deg, const unsigned short* __restrict__ colu,
    const unsigned short* __restrict__ WT,   // [16*NT][192]
    const float* __restrict__ bias,          // [16*NT]
    unsigned short* __restrict__ out_bf, float* __restrict__ out_f) {
    __shared__ unsigned short Asm[16][200];
    __shared__ unsigned short cols[16 * LSTR];
    const int i0 = blockIdx.x * 16;
    const int t = threadIdx.x;

    if (WRITE_BF16 && blockIdx.x == 0 && t < 12) {
        uint4 z = make_uint4(0, 0, 0, 0);
        *reinterpret_cast<uint4*>(out_bf + (size_t)ZROW * 96 + t * 8) = z;
    }

    // ---- stage + sanitize adjacency: 1024 ushorts, 4 per thread ----
    {
        int u4 = t * 4;                      // ushort index 0..1020
        int node = u4 >> 6;                  // CAP=64
        int slot = u4 & 63;
        uint2 v = *reinterpret_cast<const uint2*>(colu + (size_t)(i0 + node) * CAP + slot);
        int d = deg[i0 + node];
        unsigned int s0 = (slot + 0 < d) ? (v.x & 0xffffu) : ZROW;
        unsigned int s1 = (slot + 1 < d) ? (v.x >> 16)     : ZROW;
        unsigned int s2 = (slot + 2 < d) ? (v.y & 0xffffu) : ZROW;
        unsigned int s3 = (slot + 3 < d) ? (v.y >> 16)     : ZROW;
        uint2 o;
        o.x = s0 | (s1 << 16);
        o.y = s2 | (s3 << 16);
        *reinterpret_cast<uint2*>(&cols[node * LSTR + slot]) = o;
    }
    __syncthreads();

    if (t < 192) {
        const int nl = t / 12;
        const int c = (t - nl * 12) * 8;
        const int d = deg[i0 + nl];
        const int pd = (d + 7) & ~7;
        float a0 = 0.f, a1 = 0.f, a2 = 0.f, a3 = 0.f, a4 = 0.f, a5 = 0.f, a6 = 0.f, a7 = 0.f;
        for (int j = 0; j < pd; j += 8) {
            uint4 cu = *reinterpret_cast<const uint4*>(&cols[nl * LSTR + j]);
            int s0 = (int)(cu.x & 0xffffu), s1 = (int)(cu.x >> 16);
            int s2 = (int)(cu.y & 0xffffu), s3 = (int)(cu.y >> 16);
            int s4 = (int)(cu.z & 0xffffu), s5 = (int)(cu.z >> 16);
            int s6 = (int)(cu.w & 0xffffu), s7 = (int)(cu.w >> 16);
            uint4 u0 = *reinterpret_cast<const uint4*>(hb + (size_t)s0 * 96 + c);
            uint4 u1 = *reinterpret_cast<const uint4*>(hb + (size_t)s1 * 96 + c);
            uint4 u2 = *reinterpret_cast<const uint4*>(hb + (size_t)s2 * 96 + c);
            uint4 u3 = *reinterpret_cast<const uint4*>(hb + (size_t)s3 * 96 + c);
            uint4 u4 = *reinterpret_cast<const uint4*>(hb + (size_t)s4 * 96 + c);
            uint4 u5 = *reinterpret_cast<const uint4*>(hb + (size_t)s5 * 96 + c);
            uint4 u6 = *reinterpret_cast<const uint4*>(hb + (size_t)s6 * 96 + c);
            uint4 u7 = *reinterpret_cast<const uint4*>(hb + (size_t)s7 * 96 + c);
            a0 += bf2f_lo(u0.x) + bf2f_lo(u1.x) + bf2f_lo(u2.x) + bf2f_lo(u3.x)
                + bf2f_lo(u4.x) + bf2f_lo(u5.x) + bf2f_lo(u6.x) + bf2f_lo(u7.x);
            a1 += bf2f_hi(u0.x) + bf2f_hi(u1.x) + bf2f_hi(u2.x) + bf2f_hi(u3.x)
                + bf2f_hi(u4.x) + bf2f_hi(u5.x) + bf2f_hi(u6.x) + bf2f_hi(u7.x);
            a2 += bf2f_lo(u0.y) + bf2f_lo(u1.y) + bf2f_lo(u2.y) + bf2f_lo(u3.y)
                + bf2f_lo(u4.y) + bf2f_lo(u5.y) + bf2f_lo(u6.y) + bf2f_lo(u7.y);
            a3 += bf2f_hi(u0.y) + bf2f_hi(u1.y) + bf2f_hi(u2.y) + bf2f_hi(u3.y)
                + bf2f_hi(u4.y) + bf2f_hi(u5.y) + bf2f_hi(u6.y) + bf2f_hi(u7.y);
            a4 += bf2f_lo(u0.z) + bf2f_lo(u1.z) + bf2f_lo(u2.z) + bf2f_lo(u3.z)
                + bf2f_lo(u4.z) + bf2f_lo(u5.z) + bf2f_lo(u6.z) + bf2f_lo(u7.z);
            a5 += bf2f_hi(u0.z) + bf2f_hi(u1.z) + bf2f_hi(u2.z) + bf2f_hi(u3.z)
                + bf2f_hi(u4.z) + bf2f_hi(u5.z) + bf2f_hi(u6.z) + bf2f_hi(u7.z);
            a6 += bf2f_lo(u0.w) + bf2f_lo(u1.w) + bf2f_lo(u2.w) + bf2f_lo(u3.w)
                + bf2f_lo(u4.w) + bf2f_lo(u5.w) + bf2f_lo(u6.w) + bf2f_lo(u7.w);
            a7 += bf2f_hi(u0.w) + bf2f_hi(u1.w) + bf2f_hi(u2.w) + bf2f_hi(u3.w)
                + bf2f_hi(u4.w) + bf2f_hi(u5.w) + bf2f_hi(u6.w) + bf2f_hi(u7.w);
        }
        float inv = (d > 0) ? 1.0f / (float)d : 0.0f;
        uint4 o;
        o.x = (unsigned)f2bf(a0 * inv) | ((unsigned)f2bf(a1 * inv) << 16);
        o.y = (unsigned)f2bf(a2 * inv) | ((unsigned)f2bf(a3 * inv) << 16);
        o.z = (unsigned)f2bf(a4 * inv) | ((unsigned)f2bf(a5 * inv) << 16);
        o.w = (unsigned)f2bf(a6 * inv) | ((unsigned)f2bf(a7 * inv) << 16);
        *reinterpret_cast<uint4*>(&Asm[nl][c]) = o;
    }
    __syncthreads();

    const int wave = t >> 6;
    const int lane = t & 63;
    const int m = lane & 15;
    const int kq = (lane >> 4) * 8;

    bf16x8 afr[6];
#pragma unroll
    for (int kk = 0; kk < 3; ++kk)
        afr[kk] = *reinterpret_cast<const bf16x8*>(&Asm[m][kq + kk * 32]);
    const unsigned short* hrow = hb + (size_t)(i0 + m) * 96 + kq;
#pragma unroll
    for (int kk = 0; kk < 3; ++kk)
        afr[3 + kk] = *reinterpret_cast<const bf16x8*>(hrow + kk * 32);

    const int r0 = (lane >> 4) * 4;
    for (int nt = wave; nt < NT; nt += 4) {
        f32x4 acc = {0.f, 0.f, 0.f, 0.f};
        const unsigned short* wrow = WT + (size_t)(nt * 16 + m) * 192 + kq;
#pragma unroll
        for (int kk = 0; kk < 6; ++kk) {
            bf16x8 bfr = *reinterpret_cast<const bf16x8*>(wrow + kk * 32);
            acc = __builtin_amdgcn_mfma_f32_16x16x32_bf16(afr[kk], bfr, acc, 0, 0, 0);
        }
        int colj = nt * 16 + m;
        float bv = bias[colj];
#pragma unroll
        for (int r = 0; r < 4; ++r) {
            float v = fmaxf(acc[r] + bv, 0.0f);
            size_t oi = (size_t)(i0 + r0 + r) * (16 * NT) + colj;
            if (WRITE_BF16) out_bf[oi] = f2bf(v);
            else            out_f[oi] = v;
        }
    }
}

extern "C" void kernel_launch(void* const* d_in, const int* in_sizes, int n_in,
                              void* d_out, int out_size, void* d_ws, size_t ws_size,
                              hipStream_t stream) {
    const float* x   = (const float*)d_in[0];
    const int*   ei  = (const int*)d_in[1];   // [2, E]: row0 = src, row1 = dst
    const float* Wl0 = (const float*)d_in[2];
    const float* Wr0 = (const float*)d_in[3];
    const float* b0  = (const float*)d_in[4];
    const float* Wl1 = (const float*)d_in[5];
    const float* Wr1 = (const float*)d_in[6];
    const float* b1  = (const float*)d_in[7];
    const float* Wl2 = (const float*)d_in[8];
    const float* Wr2 = (const float*)d_in[9];
    const float* b2  = (const float*)d_in[10];
    float* out = (float*)d_out;

    const int* src = ei;
    const int* dst = ei + NEDGES;

    // workspace layout (all sizes multiples of 64 B)
    char* p = (char*)d_ws;
    int* deg = (int*)p;                        p += (size_t)50176 * 4;        // 200 KB
    unsigned short* colu = (unsigned short*)p; p += (size_t)50176 * CAP * 2;  // 6.4 MB
    unsigned char* cnta = (unsigned char*)p;   p += (size_t)NBKT * EBA;       // 204800 B
    unsigned short* WT0 = (unsigned short*)p;  p += 96 * 192 * 2;
    unsigned short* WT1 = (unsigned short*)p;  p += 96 * 192 * 2;
    unsigned short* WT2 = (unsigned short*)p;  p += 48 * 192 * 2;
    unsigned short* h0b = (unsigned short*)p;  p += (size_t)NROWS * 96 * 2 + 64;
    unsigned short* h1b = (unsigned short*)p;  p += (size_t)NROWS * 96 * 2 + 64;
    unsigned short* h2b = (unsigned short*)p;  p += (size_t)NROWS * 96 * 2 + 64;

    // region (EBA*NBKT*SEGC*4 = 16.38 MB) aliases h1b+h2b (19.2 MB): region is
    // dead after build_b; h1b/h2b are first written by the layer kernels after.
    unsigned int* region = (unsigned int*)h1b;

    // ---- phase A: fine-bucket edges + converts (one grid, LDS atomics only) ----
    build_a<<<EBA + CB + WB + 1, 256, 0, stream>>>(
        src, dst, region, cnta, x, h0b,
        Wl0, Wr0, Wl1, Wr1, Wl2, Wr2, WT0, WT1, WT2);

    // ---- phase B: one bucket per block, LDS-atomic slotting, coalesced dump ----
    build_b<<<NBKB, 256, 0, stream>>>(region, cnta, deg, colu);

    // ---- layers (fused gather + MFMA), 16 nodes / 256 threads per block ----
    const int LB = NNODES / 16;   // 3125 exact
    fused_layer<6, true><<<LB, 256, 0, stream>>>(h0b, deg, colu, WT0, b0, h1b, nullptr);
    fused_layer<6, true><<<LB, 256, 0, stream>>>(h1b, deg, colu, WT1, b1, h2b, nullptr);
    fused_layer<3, false><<<LB, 256, 0, stream>>>(h2b, deg, colu, WT2, b2, nullptr, out);
}